// Round 5
// baseline (286.082 us; speedup 1.0000x reference)
//
#include <hip/hip_runtime.h>
#include <math.h>

// ---------------------------------------------------------------------------
// NFFT forward (type-2): f_hat (B,C,256,256 complex) -> samples at M points.
// Pipeline: deconvolve+pad+fftshift -> 2D FFT 512x512 -> windowed gather.
// Shift algebra: ifftshift(FFT(fftshift(p)))[(ind+256)%512] == FFT(fftshift(p))[ind&511].
// Output PLANAR: real plane (B,C,M) then imag plane.
// NOTE (round-4 post-mortem): do NOT force __launch_bounds__ minima that
// induce spills — a spilling kernel never wrote output under this harness.
// stage/fft_rows/fft_cols below are byte-identical to the round-3 PASS.
// ---------------------------------------------------------------------------

#define NGRID 512
#define NSMALL 256
#define MW 4
#define BB 2
#define CC 2
#define MPTS 200000
#define PLANE (BB * CC * MPTS)   // imag-plane offset in floats

// I0(z) asymptotic series, valid z > 8 (our z in [17.7, 18.9])
__device__ __forceinline__ float nfft29781_i0_large(float z) {
    float inv = 1.0f / z;
    float p = 1.0f + inv * (0.125f + inv * (0.0703125f
              + inv * (0.0732421875f + inv * 0.112152099609375f)));
    return expf(z) * rsqrtf(2.0f * (float)M_PI * z) * p;
}

// ---------------------------------------------------------------------------
// Stage (round-3 verbatim): G = fftshift(pad(f_hat/phi_hat)), writes all elems.
// ---------------------------------------------------------------------------
__global__ __launch_bounds__(256) void nfft29781_stage(const float* __restrict__ fr,
                                                       const float* __restrict__ fi,
                                                       float2* __restrict__ G,
                                                       int img0, int nimg) {
    int t = blockIdx.x * blockDim.x + threadIdx.x;
    if (t >= nimg * NGRID * NGRID) return;
    int j2 = t & (NGRID - 1);
    int j1 = (t >> 9) & (NGRID - 1);
    int img = img0 + (t >> 18);

    float2 v = make_float2(0.0f, 0.0f);
    int a1 = -1, a2 = -1;
    if (j1 < 128) a1 = j1 + 128; else if (j1 >= 384) a1 = j1 - 384;
    if (j2 < 128) a2 = j2 + 128; else if (j2 >= 384) a2 = j2 - 384;
    if (a1 >= 0 && a2 >= 0) {
        const float bcon = 1.5f * (float)M_PI;
        const float scale = 2.0f * (float)M_PI / (float)NGRID;
        float k1 = (float)(a1 - 128) * scale;
        float k2 = (float)(a2 - 128) * scale;
        float ph = nfft29781_i0_large((float)MW * sqrtf(bcon * bcon - k1 * k1))
                 * nfft29781_i0_large((float)MW * sqrtf(bcon * bcon - k2 * k2));
        size_t src = ((size_t)img * NSMALL + a1) * NSMALL + a2;
        float s = 1.0f / ph;
        v.x = fr[src] * s;
        v.y = fi[src] * s;
    }
    G[t] = v;
}

// ---------------------------------------------------------------------------
// 512-pt radix-2 DIT FFT in LDS (round-3 verbatim).
// ---------------------------------------------------------------------------
__device__ __forceinline__ void nfft29781_fft512(float2* s, int tid) {
    #pragma unroll
    for (int st = 0; st < 9; ++st) {
        int half = 1 << st;
        int pos = tid & (half - 1);
        int i0 = ((tid >> st) << (st + 1)) + pos;
        int i1 = i0 + half;
        float ang = -(float)M_PI * (float)pos / (float)half;
        float sn, cs;
        sincosf(ang, &sn, &cs);
        float2 a = s[i0];
        float2 b = s[i1];
        float2 tw = make_float2(b.x * cs - b.y * sn, b.x * sn + b.y * cs);
        s[i0] = make_float2(a.x + tw.x, a.y + tw.y);
        s[i1] = make_float2(a.x - tw.x, a.y - tw.y);
        __syncthreads();
    }
}

__global__ __launch_bounds__(256) void nfft29781_fft_rows(float2* __restrict__ G) {
    __shared__ float2 s[NGRID];
    size_t base = (size_t)blockIdx.x * NGRID;
    int tid = threadIdx.x;
    s[__brev((unsigned)tid) >> 23] = G[base + tid];
    s[__brev((unsigned)(tid + 256)) >> 23] = G[base + tid + 256];
    __syncthreads();
    nfft29781_fft512(s, tid);
    G[base + tid] = s[tid];
    G[base + tid + 256] = s[tid + 256];
}

__global__ __launch_bounds__(256) void nfft29781_fft_cols(float2* __restrict__ G) {
    __shared__ float2 s[NGRID];
    int col = blockIdx.x & (NGRID - 1);
    int img = blockIdx.x >> 9;
    size_t base = (size_t)img * NGRID * NGRID + col;
    int tid = threadIdx.x;
    s[__brev((unsigned)tid) >> 23] = G[base + (size_t)tid * NGRID];
    s[__brev((unsigned)(tid + 256)) >> 23] = G[base + (size_t)(tid + 256) * NGRID];
    __syncthreads();
    nfft29781_fft512(s, tid);
    G[base + (size_t)tid * NGRID] = s[tid];
    G[base + (size_t)(tid + 256) * NGRID] = s[tid + 256];
}

// ---------------------------------------------------------------------------
// Kaiser-Bessel per-dim weights (bit-matches reference ceil(x*n)-m sequence).
// ---------------------------------------------------------------------------
__device__ __forceinline__ void nfft29781_weights(float u, int& base, float* w) {
    float c = ceilf(u);
    base = (int)c - MW;
    float d = c - u;
    const float bw = 1.5f * (float)M_PI;
    const float invpi = 1.0f / (float)M_PI;
    #pragma unroll
    for (int i = 0; i < 8; ++i) {
        float nk = (float)(MW - i) - d;
        float tt = (float)(MW * MW) - nk * nk;
        float wv = 0.0f;
        if (tt > 0.0f) {
            float a = sqrtf(tt);
            float e = expf(bw * a);
            wv = (e - 1.0f / e) * 0.5f * invpi / a;
        }
        w[i] = wv;
    }
}

// ---------------------------------------------------------------------------
// Split gather: ONE (b,c) image per thread (4*M threads). Halves per-thread
// live state vs round 3 (one acc pair, 64 tap loads) -> lower VGPR, higher
// occupancy, no forced launch bounds (no spill risk). out[t]/out[PLANE+t]
// writes are coalesced; guards identical in style to the round-3 pass.
// ---------------------------------------------------------------------------
__global__ __launch_bounds__(256) void nfft29781_gather_split(const float* __restrict__ x,
                                                              const float2* __restrict__ G,
                                                              float* __restrict__ out,
                                                              int out_elems) {
    int t = blockIdx.x * blockDim.x + threadIdx.x;
    if (t >= BB * CC * MPTS) return;
    int img = t / MPTS;                 // b*CC + c
    int pt  = t - img * MPTS;
    int b   = img >> 1;                 // CC == 2

    size_t xi = (size_t)(b * MPTS + pt) * 2;
    float u0 = x[xi + 0] * (float)NGRID;
    float u1 = x[xi + 1] * (float)NGRID;
    int base0, base1;
    float w0[8], w1[8];
    nfft29781_weights(u0, base0, w0);
    nfft29781_weights(u1, base1, w1);

    const float2* Gi = G + (size_t)img * NGRID * NGRID;
    float accx = 0.0f, accy = 0.0f;
    #pragma unroll
    for (int i = 0; i < 8; ++i) {
        float wi = w0[i];
        int rowoff = ((base0 + i) & (NGRID - 1)) << 9;
        #pragma unroll
        for (int j = 0; j < 8; ++j) {
            float w = wi * w1[j];
            int cix = (base1 + j) & (NGRID - 1);
            float2 g = Gi[rowoff + cix];
            accx += w * g.x;
            accy += w * g.y;
        }
    }

    size_t o = (size_t)t;               // img*MPTS + pt
    if (o < (size_t)out_elems)         out[o]         = accx;
    if (PLANE + o < (size_t)out_elems) out[PLANE + o] = accy;
}

extern "C" void kernel_launch(void* const* d_in, const int* in_sizes, int n_in,
                              void* d_out, int out_size, void* d_ws, size_t ws_size,
                              hipStream_t stream) {
    (void)in_sizes; (void)n_in;
    const float* x  = (const float*)d_in[0];
    const float* fr = (const float*)d_in[1];
    const float* fi = (const float*)d_in[2];
    float*  out = (float*)d_out;
    float2* G   = (float2*)d_ws;        // BB*CC*512*512 complex = 8 MB

    const size_t fullBytes = (size_t)BB * CC * NGRID * NGRID * sizeof(float2);
    if (ws_size < fullBytes) return;    // diagnostic no-op (ws proven >= 8 MB in R3)

    int total = BB * CC * NGRID * NGRID;
    nfft29781_stage<<<(total + 255) / 256, 256, 0, stream>>>(fr, fi, G, 0, BB * CC);
    nfft29781_fft_rows<<<BB * CC * NGRID, 256, 0, stream>>>(G);
    nfft29781_fft_cols<<<BB * CC * NGRID, 256, 0, stream>>>(G);
    nfft29781_gather_split<<<(BB * CC * MPTS + 255) / 256, 256, 0, stream>>>(x, G, out, out_size);
}

// Round 6
// 144.572 us; speedup vs baseline: 1.9788x; 1.9788x over previous
//
#include <hip/hip_runtime.h>
#include <math.h>

// ---------------------------------------------------------------------------
// NFFT forward (type-2): f_hat (B,C,256,256 complex) -> samples at M points.
// Pipeline: deconvolve+pad+fftshift -> 2D FFT 512x512 -> windowed gather.
// Shift algebra: ifftshift(FFT(fftshift(p)))[(ind+256)%512] == FFT(fftshift(p))[ind&511].
// Output PLANAR: real plane (B,C,M) then imag plane.
// R4 lesson: no forced __launch_bounds__ minima (spill -> dead kernel).
// R5 lesson: gather is L1-transaction bound (64 lanes x 64 distinct lines per
// wave-load). This round: 8 lanes per point -> 64B-contiguous per-group reads
// coalesce in the TA (~5x fewer line-requests). FFT path = round-3 verbatim.
// ---------------------------------------------------------------------------

#define NGRID 512
#define NSMALL 256
#define MW 4
#define BB 2
#define CC 2
#define MPTS 200000
#define PLANE (BB * CC * MPTS)   // imag-plane offset in floats

// I0(z) asymptotic series, valid z > 8 (our z in [17.7, 18.9])
__device__ __forceinline__ float nfft29781_i0_large(float z) {
    float inv = 1.0f / z;
    float p = 1.0f + inv * (0.125f + inv * (0.0703125f
              + inv * (0.0732421875f + inv * 0.112152099609375f)));
    return expf(z) * rsqrtf(2.0f * (float)M_PI * z) * p;
}

// ---------------------------------------------------------------------------
// Stage (round-3 verbatim): G = fftshift(pad(f_hat/phi_hat)), writes all elems.
// ---------------------------------------------------------------------------
__global__ __launch_bounds__(256) void nfft29781_stage(const float* __restrict__ fr,
                                                       const float* __restrict__ fi,
                                                       float2* __restrict__ G,
                                                       int img0, int nimg) {
    int t = blockIdx.x * blockDim.x + threadIdx.x;
    if (t >= nimg * NGRID * NGRID) return;
    int j2 = t & (NGRID - 1);
    int j1 = (t >> 9) & (NGRID - 1);
    int img = img0 + (t >> 18);

    float2 v = make_float2(0.0f, 0.0f);
    int a1 = -1, a2 = -1;
    if (j1 < 128) a1 = j1 + 128; else if (j1 >= 384) a1 = j1 - 384;
    if (j2 < 128) a2 = j2 + 128; else if (j2 >= 384) a2 = j2 - 384;
    if (a1 >= 0 && a2 >= 0) {
        const float bcon = 1.5f * (float)M_PI;
        const float scale = 2.0f * (float)M_PI / (float)NGRID;
        float k1 = (float)(a1 - 128) * scale;
        float k2 = (float)(a2 - 128) * scale;
        float ph = nfft29781_i0_large((float)MW * sqrtf(bcon * bcon - k1 * k1))
                 * nfft29781_i0_large((float)MW * sqrtf(bcon * bcon - k2 * k2));
        size_t src = ((size_t)img * NSMALL + a1) * NSMALL + a2;
        float s = 1.0f / ph;
        v.x = fr[src] * s;
        v.y = fi[src] * s;
    }
    G[t] = v;
}

// ---------------------------------------------------------------------------
// 512-pt radix-2 DIT FFT in LDS (round-3 verbatim).
// ---------------------------------------------------------------------------
__device__ __forceinline__ void nfft29781_fft512(float2* s, int tid) {
    #pragma unroll
    for (int st = 0; st < 9; ++st) {
        int half = 1 << st;
        int pos = tid & (half - 1);
        int i0 = ((tid >> st) << (st + 1)) + pos;
        int i1 = i0 + half;
        float ang = -(float)M_PI * (float)pos / (float)half;
        float sn, cs;
        sincosf(ang, &sn, &cs);
        float2 a = s[i0];
        float2 b = s[i1];
        float2 tw = make_float2(b.x * cs - b.y * sn, b.x * sn + b.y * cs);
        s[i0] = make_float2(a.x + tw.x, a.y + tw.y);
        s[i1] = make_float2(a.x - tw.x, a.y - tw.y);
        __syncthreads();
    }
}

__global__ __launch_bounds__(256) void nfft29781_fft_rows(float2* __restrict__ G) {
    __shared__ float2 s[NGRID];
    size_t base = (size_t)blockIdx.x * NGRID;
    int tid = threadIdx.x;
    s[__brev((unsigned)tid) >> 23] = G[base + tid];
    s[__brev((unsigned)(tid + 256)) >> 23] = G[base + tid + 256];
    __syncthreads();
    nfft29781_fft512(s, tid);
    G[base + tid] = s[tid];
    G[base + tid + 256] = s[tid + 256];
}

__global__ __launch_bounds__(256) void nfft29781_fft_cols(float2* __restrict__ G) {
    __shared__ float2 s[NGRID];
    int col = blockIdx.x & (NGRID - 1);
    int img = blockIdx.x >> 9;
    size_t base = (size_t)img * NGRID * NGRID + col;
    int tid = threadIdx.x;
    s[__brev((unsigned)tid) >> 23] = G[base + (size_t)tid * NGRID];
    s[__brev((unsigned)(tid + 256)) >> 23] = G[base + (size_t)(tid + 256) * NGRID];
    __syncthreads();
    nfft29781_fft512(s, tid);
    G[base + (size_t)tid * NGRID] = s[tid];
    G[base + (size_t)tid * NGRID + 0] = s[tid];   // (idempotent; kept simple)
    G[base + (size_t)(tid + 256) * NGRID] = s[tid + 256];
}

// ---------------------------------------------------------------------------
// Coalesced gather: 8 lanes per (point,image). Lane j of each aligned 8-lane
// group owns column-tap j; per row the group reads 64 contiguous bytes ->
// TA coalesces. w0[i] broadcast via __shfl from lane base+i; sum over j via
// 3-stage __shfl_xor butterfly; lane j==0 writes planar out (coalesced).
// Weight sequence bit-matches reference ceil(x*n)-m.
// ---------------------------------------------------------------------------
__global__ __launch_bounds__(256) void nfft29781_gather_coal(const float* __restrict__ x,
                                                             const float2* __restrict__ G,
                                                             float* __restrict__ out,
                                                             int out_elems) {
    int t = blockIdx.x * blockDim.x + threadIdx.x;
    int j  = t & 7;                  // my column tap
    int pp = t >> 3;                 // (img, point) id
    if (pp >= BB * CC * MPTS) return;
    int img = pp / MPTS;             // b*CC + c
    int pt  = pp - img * MPTS;
    int b   = img >> 1;              // CC == 2

    size_t xi = (size_t)(b * MPTS + pt) * 2;
    float u0 = x[xi + 0] * (float)NGRID;   // 8 lanes same addr -> broadcast
    float u1 = x[xi + 1] * (float)NGRID;

    float c0 = ceilf(u0), c1 = ceilf(u1);
    int base0 = (int)c0 - MW;
    int base1 = (int)c1 - MW;
    float d0 = c0 - u0, d1 = c1 - u1;

    const float bw = 1.5f * (float)M_PI;
    const float invpi = 1.0f / (float)M_PI;
    float w0m, w1m;   // my dim-0 tap-j weight, my dim-1 tap-j weight
    {
        float nk = (float)(MW - j) - d0;
        float tt = (float)(MW * MW) - nk * nk;
        w0m = 0.0f;
        if (tt > 0.0f) { float a = sqrtf(tt); float e = expf(bw * a);
                         w0m = (e - 1.0f / e) * 0.5f * invpi / a; }
        nk = (float)(MW - j) - d1;
        tt = (float)(MW * MW) - nk * nk;
        w1m = 0.0f;
        if (tt > 0.0f) { float a = sqrtf(tt); float e = expf(bw * a);
                         w1m = (e - 1.0f / e) * 0.5f * invpi / a; }
    }

    const float2* Gi = G + (size_t)img * NGRID * NGRID;
    int cix = (base1 + j) & (NGRID - 1);
    int lanebase = (threadIdx.x & 63) & ~7;    // my group's base lane

    float accx = 0.0f, accy = 0.0f;
    #pragma unroll
    for (int i = 0; i < 8; ++i) {
        float w0i = __shfl(w0m, lanebase + i, 64);   // row-i weight (from lane base+i)
        int row = (base0 + i) & (NGRID - 1);
        float2 g = Gi[(row << 9) + cix];
        accx += w0i * g.x;
        accy += w0i * g.y;
    }
    accx *= w1m;
    accy *= w1m;

    #pragma unroll
    for (int msk = 1; msk < 8; msk <<= 1) {    // sum over the 8 column taps
        accx += __shfl_xor(accx, msk, 64);
        accy += __shfl_xor(accy, msk, 64);
    }

    if (j == 0) {
        size_t o = (size_t)pp;                 // img*MPTS + pt
        if (o < (size_t)out_elems)         out[o]         = accx;
        if (PLANE + o < (size_t)out_elems) out[PLANE + o] = accy;
    }
}

extern "C" void kernel_launch(void* const* d_in, const int* in_sizes, int n_in,
                              void* d_out, int out_size, void* d_ws, size_t ws_size,
                              hipStream_t stream) {
    (void)in_sizes; (void)n_in;
    const float* x  = (const float*)d_in[0];
    const float* fr = (const float*)d_in[1];
    const float* fi = (const float*)d_in[2];
    float*  out = (float*)d_out;
    float2* G   = (float2*)d_ws;        // BB*CC*512*512 complex = 8 MB

    const size_t fullBytes = (size_t)BB * CC * NGRID * NGRID * sizeof(float2);
    if (ws_size < fullBytes) return;    // diagnostic no-op (ws proven >= 8 MB)

    int total = BB * CC * NGRID * NGRID;
    nfft29781_stage<<<(total + 255) / 256, 256, 0, stream>>>(fr, fi, G, 0, BB * CC);
    nfft29781_fft_rows<<<BB * CC * NGRID, 256, 0, stream>>>(G);
    nfft29781_fft_cols<<<BB * CC * NGRID, 256, 0, stream>>>(G);
    int gthreads = BB * CC * MPTS * 8;  // 8 lanes per (img,point)
    nfft29781_gather_coal<<<(gthreads + 255) / 256, 256, 0, stream>>>(x, G, out, out_size);
}

// Round 7
// 130.041 us; speedup vs baseline: 2.1999x; 1.1117x over previous
//
#include <hip/hip_runtime.h>
#include <math.h>

// ---------------------------------------------------------------------------
// NFFT forward (type-2): f_hat (B,C,256,256 complex) -> samples at M points.
// Pipeline (2 FFT launches + gather):
//   rows: fused deconvolve/pad/fftshift -> 512-pt row FFT over the 256
//         nonzero staged rows per image only (middle 256 rows are zero).
//   cols: 512-pt col FFT; reads the 256 nonzero rows, injects zeros for the
//         middle rows (never written), writes all 512. One block per column.
//   gather (round-6 verbatim): 8 lanes per (img,point), coalesced taps.
// Shift algebra: ifftshift(FFT(fftshift(p)))[(ind+256)%512] == FFT(fftshift(p))[ind&511].
// Output PLANAR: real plane (B,C,M) then imag plane.
// R4 lesson: no forced __launch_bounds__ minima (spill -> dead kernel).
// R5 lesson: scattered per-lane gather is L1-transaction bound -> coalesce.
// ---------------------------------------------------------------------------

#define NGRID 512
#define NSMALL 256
#define MW 4
#define BB 2
#define CC 2
#define MPTS 200000
#define PLANE (BB * CC * MPTS)   // imag-plane offset in floats

// I0(z) asymptotic series, valid z > 8 (our z in [17.7, 18.9])
__device__ __forceinline__ float nfft29781_i0_large(float z) {
    float inv = 1.0f / z;
    float p = 1.0f + inv * (0.125f + inv * (0.0703125f
              + inv * (0.0732421875f + inv * 0.112152099609375f)));
    return expf(z) * rsqrtf(2.0f * (float)M_PI * z) * p;
}

__device__ __forceinline__ int nfft29781_brev9(int v) {
    return (int)(__brev((unsigned)v) >> 23);
}

// 512-pt radix-2 DIT FFT in LDS (input pre-loaded bit-reversed).
__device__ __forceinline__ void nfft29781_fft512(float2* s, int tid) {
    #pragma unroll
    for (int st = 0; st < 9; ++st) {
        int half = 1 << st;
        int pos = tid & (half - 1);
        int i0 = ((tid >> st) << (st + 1)) + pos;
        int i1 = i0 + half;
        float ang = -(float)M_PI * (float)pos / (float)half;
        float sn, cs;
        __sincosf(ang, &sn, &cs);
        float2 a = s[i0];
        float2 b = s[i1];
        float2 tw = make_float2(b.x * cs - b.y * sn, b.x * sn + b.y * cs);
        s[i0] = make_float2(a.x + tw.x, a.y + tw.y);
        s[i1] = make_float2(a.x - tw.x, a.y - tw.y);
        __syncthreads();
    }
}

// ---------------------------------------------------------------------------
// Rows: one block per (img, a1), a1 in [0,256) = f_hat row. Staged row
// j1 = (a1<128)? a1+384 : a1-128. Thread tid owns staged cols tid and
// tid+256; exactly one is nonzero with f_hat col a2 = tid ^ 128.
// Value = f_hat/(phi1*phi2). FFT, store to G row j1 (512 cols).
// ---------------------------------------------------------------------------
__global__ __launch_bounds__(256) void nfft29781_rows_fused(const float* __restrict__ fr,
                                                            const float* __restrict__ fi,
                                                            float2* __restrict__ G) {
    __shared__ float2 s[NGRID];
    int tid = threadIdx.x;
    int img = blockIdx.x >> 8;
    int a1  = blockIdx.x & 255;

    const float bcon  = 1.5f * (float)M_PI;
    const float scale = 2.0f * (float)M_PI / (float)NGRID;
    float k1 = (float)(a1 - 128) * scale;
    float p1 = nfft29781_i0_large((float)MW * sqrtf(bcon * bcon - k1 * k1));

    int a2 = tid ^ 128;
    float k2 = (float)(a2 - 128) * scale;
    float p2 = nfft29781_i0_large((float)MW * sqrtf(bcon * bcon - k2 * k2));

    size_t src = ((size_t)img * NSMALL + a1) * NSMALL + a2;
    float invp = 1.0f / (p1 * p2);
    float2 v = make_float2(fr[src] * invp, fi[src] * invp);

    int j2v = (tid < 128) ? tid : tid + 256;        // nonzero staged col
    int j2z = (tid < 128) ? tid + 256 : tid;        // zero staged col
    s[nfft29781_brev9(j2v)] = v;
    s[nfft29781_brev9(j2z)] = make_float2(0.0f, 0.0f);
    __syncthreads();

    nfft29781_fft512(s, tid);

    int j1 = (a1 < 128) ? a1 + 384 : a1 - 128;      // staged row (fftshift fold)
    size_t base = ((size_t)img * NGRID + j1) * NGRID;
    G[base + tid]       = s[tid];
    G[base + tid + 256] = s[tid + 256];
}

// ---------------------------------------------------------------------------
// Cols: one block per (img, col). Middle rows [128,384) are structurally zero
// (never written by rows_fused) -> inject zeros. Block owns its column.
// ---------------------------------------------------------------------------
__global__ __launch_bounds__(256) void nfft29781_cols(float2* __restrict__ G) {
    __shared__ float2 s[NGRID];
    int tid = threadIdx.x;
    int col = blockIdx.x & (NGRID - 1);
    int img = blockIdx.x >> 9;
    size_t base = (size_t)img * NGRID * NGRID + col;

    int r0 = tid, r1 = tid + 256;
    float2 v0 = (r0 >= 128) ? make_float2(0.0f, 0.0f) : G[base + (size_t)r0 * NGRID];
    float2 v1 = (r1 <  384) ? make_float2(0.0f, 0.0f) : G[base + (size_t)r1 * NGRID];
    s[nfft29781_brev9(r0)] = v0;
    s[nfft29781_brev9(r1)] = v1;
    __syncthreads();

    nfft29781_fft512(s, tid);

    G[base + (size_t)r0 * NGRID] = s[r0];
    G[base + (size_t)r1 * NGRID] = s[r1];
}

// ---------------------------------------------------------------------------
// Coalesced gather (round-6 verbatim): 8 lanes per (point,image). Lane j owns
// column-tap j; per row the group reads 64 contiguous bytes. w0[i] broadcast
// via __shfl; 3-stage __shfl_xor butterfly sums the 8 taps; lane 0 writes.
// ---------------------------------------------------------------------------
__global__ __launch_bounds__(256) void nfft29781_gather_coal(const float* __restrict__ x,
                                                             const float2* __restrict__ G,
                                                             float* __restrict__ out,
                                                             int out_elems) {
    int t = blockIdx.x * blockDim.x + threadIdx.x;
    int j  = t & 7;                  // my column tap
    int pp = t >> 3;                 // (img, point) id
    if (pp >= BB * CC * MPTS) return;
    int img = pp / MPTS;             // b*CC + c
    int pt  = pp - img * MPTS;
    int b   = img >> 1;              // CC == 2

    size_t xi = (size_t)(b * MPTS + pt) * 2;
    float u0 = x[xi + 0] * (float)NGRID;   // 8 lanes same addr -> broadcast
    float u1 = x[xi + 1] * (float)NGRID;

    float c0 = ceilf(u0), c1 = ceilf(u1);
    int base0 = (int)c0 - MW;
    int base1 = (int)c1 - MW;
    float d0 = c0 - u0, d1 = c1 - u1;

    const float bw = 1.5f * (float)M_PI;
    const float invpi = 1.0f / (float)M_PI;
    float w0m, w1m;   // my dim-0 tap-j weight, my dim-1 tap-j weight
    {
        float nk = (float)(MW - j) - d0;
        float tt = (float)(MW * MW) - nk * nk;
        w0m = 0.0f;
        if (tt > 0.0f) { float a = sqrtf(tt); float e = expf(bw * a);
                         w0m = (e - 1.0f / e) * 0.5f * invpi / a; }
        nk = (float)(MW - j) - d1;
        tt = (float)(MW * MW) - nk * nk;
        w1m = 0.0f;
        if (tt > 0.0f) { float a = sqrtf(tt); float e = expf(bw * a);
                         w1m = (e - 1.0f / e) * 0.5f * invpi / a; }
    }

    const float2* Gi = G + (size_t)img * NGRID * NGRID;
    int cix = (base1 + j) & (NGRID - 1);
    int lanebase = (threadIdx.x & 63) & ~7;    // my group's base lane

    float accx = 0.0f, accy = 0.0f;
    #pragma unroll
    for (int i = 0; i < 8; ++i) {
        float w0i = __shfl(w0m, lanebase + i, 64);   // row-i weight
        int row = (base0 + i) & (NGRID - 1);
        float2 g = Gi[(row << 9) + cix];
        accx += w0i * g.x;
        accy += w0i * g.y;
    }
    accx *= w1m;
    accy *= w1m;

    #pragma unroll
    for (int msk = 1; msk < 8; msk <<= 1) {    // sum over the 8 column taps
        accx += __shfl_xor(accx, msk, 64);
        accy += __shfl_xor(accy, msk, 64);
    }

    if (j == 0) {
        size_t o = (size_t)pp;                 // img*MPTS + pt
        if (o < (size_t)out_elems)         out[o]         = accx;
        if (PLANE + o < (size_t)out_elems) out[PLANE + o] = accy;
    }
}

extern "C" void kernel_launch(void* const* d_in, const int* in_sizes, int n_in,
                              void* d_out, int out_size, void* d_ws, size_t ws_size,
                              hipStream_t stream) {
    (void)in_sizes; (void)n_in;
    const float* x  = (const float*)d_in[0];
    const float* fr = (const float*)d_in[1];
    const float* fi = (const float*)d_in[2];
    float*  out = (float*)d_out;
    float2* G   = (float2*)d_ws;        // BB*CC*512*512 complex = 8 MB

    const size_t fullBytes = (size_t)BB * CC * NGRID * NGRID * sizeof(float2);
    if (ws_size < fullBytes) return;    // diagnostic no-op (ws proven >= 8 MB)

    nfft29781_rows_fused<<<BB * CC * NSMALL, 256, 0, stream>>>(fr, fi, G);
    nfft29781_cols<<<BB * CC * NGRID, 256, 0, stream>>>(G);
    int gthreads = BB * CC * MPTS * 8;  // 8 lanes per (img,point)
    nfft29781_gather_coal<<<(gthreads + 255) / 256, 256, 0, stream>>>(x, G, out, out_size);
}